// Round 4
// baseline (81.768 us; speedup 1.0000x reference)
//
#include <hip/hip_runtime.h>
#include <hip/hip_bf16.h>
#include <math.h>

#define NB 32     // batch
#define NH 32     // query heads
#define HKV 8     // kv heads
#define GQ 4      // NH / HKV
#define DH 128    // head dim
#define BS 16     // paged block size
#define BPS 128   // blocks per seq
#define MAXC 2048 // max context (BPS * BS)
#define NSPLIT 32 // flash-decoding splits per (b, kvh)
#define HSTR 132  // per-head partial: acc[128], m, l, pad2
#define PART_STRIDE (GQ * HSTR)   // 528 floats per wave-partial

__device__ __forceinline__ float bf16r(float x) {
    return __bfloat162float(__float2bfloat16(x));
}

// ---------------- Kernel 1: fused rowidx + RoPE ------------------------------
// rowidx[b*MAXC + t] >= 0 : flat cache row; < 0 : -(j+1) -> new kv of batch j.
// Blocks 0..31 additionally apply bf16-cache-exact RoPE for batch bid.
__global__ void prep_kernel(const float* __restrict__ q,
                            const float* __restrict__ knew,
                            const int* __restrict__ bt,
                            const int* __restrict__ ctx,
                            float* __restrict__ q_rot,
                            float* __restrict__ k_rot,
                            int* __restrict__ rowidx)
{
    __shared__ int slot_l[NB];
    int tid = threadIdx.x, bid = blockIdx.x;
    if (tid < NB) {
        int last = ctx[tid] - 1;
        slot_l[tid] = bt[tid * BPS + (last >> 4)] * BS + (last & 15);
    }
    __syncthreads();

    int g = bid * 256 + tid;              // g = b*MAXC + t
    int b = g >> 11;
    int t = g & (MAXC - 1);
    int flat = bt[b * BPS + (t >> 4)] * BS + (t & 15);
    int o = flat;
    #pragma unroll
    for (int j = 0; j < NB; ++j)
        if (flat == slot_l[j]) o = -(j + 1);
    rowidx[g] = o;

    if (bid < NB) {                       // RoPE for batch `bid`
        int rb  = bid;
        int d   = tid & 127;              // dim
        int hi  = tid >> 7;               // 0/1: head-range split
        int pos = ctx[rb];
        int i2  = d & 63;
        // Mimic: inv = bf16(1/10000^(i/64)), t = bf16(pos), fr = bf16(t*inv),
        // cos/sin f32-computed then bf16-rounded (XLA bf16 semantics).
        float e   = (float)i2 * (1.0f / 64.0f);
        float pf  = (float)pow(10000.0, (double)e);
        float inv = bf16r(1.0f / pf);
        float tb  = bf16r((float)pos);
        float fr  = bf16r(tb * inv);
        float c   = bf16r(cosf(fr));
        float s   = bf16r(sinf(fr));

        const float* qb = q + (size_t)rb * NH * DH;
        float* qo = q_rot + (size_t)rb * NH * DH;
        #pragma unroll 4
        for (int h = hi * 16; h < hi * 16 + 16; ++h) {
            float x  = qb[h * DH + d];
            float xr = (d < 64) ? -qb[h * DH + d + 64] : qb[h * DH + d - 64];
            qo[h * DH + d] = x * c + xr * s;
        }
        const float* kb = knew + (size_t)rb * HKV * DH;
        float* ko = k_rot + (size_t)rb * HKV * DH;
        #pragma unroll
        for (int h = hi * 4; h < hi * 4 + 4; ++h) {
            float x  = kb[h * DH + d];
            float xr = (d < 64) ? -kb[h * DH + d + 64] : kb[h * DH + d - 64];
            ko[h * DH + d] = x * c + xr * s;
        }
    }
}

// ---------------- Kernel 2: attention partials, wave-independent ------------
// One wave = one (b, kvh, split) handling all GQ=4 heads in registers.
// No LDS staging, no barriers. 8-position micro-tiles:
//   lane (H = lane>>5, c = lane&31) holds K/V[t0+2i+H][c*4 .. c*4+3], i=0..3.
//   Partial dots -> 5-level __shfl_xor butterfly within each 32-lane half ->
//   every lane holds s[i][h]; online softmax per half; halves merged at end.
__global__ __launch_bounds__(256) void attn_partial(
    const float* __restrict__ kc, const float* __restrict__ vc,
    const float* __restrict__ vnew,
    const int* __restrict__ ctx,
    const float* __restrict__ q_rot, const float* __restrict__ k_rot,
    const int* __restrict__ rowidx, float* __restrict__ part)
{
    int tid = threadIdx.x;
    int bid = blockIdx.x;
    int w   = tid >> 6;                   // wave in block -> kvh low bits
    int b   = bid & (NB - 1);
    int kvh = ((bid >> 5) & 1) * 4 + w;
    int sp  = bid >> 6;                   // 0..31

    int L = ctx[b];
    int chunk = (L + NSPLIT - 1) / NSPLIT;
    int start = sp * chunk;
    int end   = min(L, start + chunk);

    int lane = tid & 63;
    int c    = lane & 31;                 // float4 column
    int H    = lane >> 5;                 // row parity half

    // q fragments: q[h][c*4 .. c*4+3] for the 4 grouped heads
    float4 qr[4];
    #pragma unroll
    for (int h = 0; h < 4; ++h)
        qr[h] = *(const float4*)(q_rot + ((size_t)b * NH + kvh * GQ + h) * DH + c * 4);

    float  m[4], l[4];
    float4 o[4];
    #pragma unroll
    for (int h = 0; h < 4; ++h) {
        m[h] = -INFINITY; l[h] = 0.f;
        o[h] = make_float4(0.f, 0.f, 0.f, 0.f);
    }

    const float scale = 0.08838834764831845f;   // D^-0.5

    for (int t0 = start; t0 < end; t0 += 8) {
        // ---- gather 8 rows (4 per half), unconditional clamped loads ----
        int src[4];
        #pragma unroll
        for (int i = 0; i < 4; ++i) {
            int t = min(t0 + 2 * i + H, end - 1);
            src[i] = rowidx[(b << 11) | t];
        }
        float4 kr[4], vr[4];
        #pragma unroll
        for (int i = 0; i < 4; ++i) {
            int oi = src[i]; int j = -oi - 1;
            const float* kp = (oi >= 0)
                ? kc + (size_t)oi * (HKV * DH) + kvh * DH
                : k_rot + ((size_t)j * HKV + kvh) * DH;
            kr[i] = ((const float4*)kp)[c];
        }
        #pragma unroll
        for (int i = 0; i < 4; ++i) {
            int oi = src[i]; int j = -oi - 1;
            const float* vp = (oi >= 0)
                ? vc + (size_t)oi * (HKV * DH) + kvh * DH
                : vnew + ((size_t)j * HKV + kvh) * DH;
            vr[i] = ((const float4*)vp)[c];
        }

        // ---- per-lane partial dots: 4 rows x 4 heads ----
        float s[4][4];
        #pragma unroll
        for (int i = 0; i < 4; ++i)
            #pragma unroll
            for (int h = 0; h < 4; ++h)
                s[i][h] = qr[h].x * kr[i].x + qr[h].y * kr[i].y
                        + qr[h].z * kr[i].z + qr[h].w * kr[i].w;

        // ---- butterfly reduce over the 32 c-lanes (within each half) ----
        #pragma unroll
        for (int lev = 1; lev <= 16; lev <<= 1)
            #pragma unroll
            for (int i = 0; i < 4; ++i)
                #pragma unroll
                for (int h = 0; h < 4; ++h)
                    s[i][h] += __shfl_xor(s[i][h], lev);

        // ---- scale + validity mask ----
        #pragma unroll
        for (int i = 0; i < 4; ++i) {
            bool valid = (t0 + 2 * i + H) < end;
            #pragma unroll
            for (int h = 0; h < 4; ++h)
                s[i][h] = valid ? s[i][h] * scale : -INFINITY;
        }

        // ---- online softmax per head (per half), PV from registers ----
        #pragma unroll
        for (int h = 0; h < 4; ++h) {
            float tm = fmaxf(fmaxf(s[0][h], s[1][h]), fmaxf(s[2][h], s[3][h]));
            float mnew = fmaxf(m[h], tm);
            if (mnew > -INFINITY) {       // uniform within a half
                float r  = __expf(m[h] - mnew);   // m=-inf -> 0
                float p0 = __expf(s[0][h] - mnew);
                float p1 = __expf(s[1][h] - mnew);
                float p2 = __expf(s[2][h] - mnew);
                float p3 = __expf(s[3][h] - mnew);
                l[h] = l[h] * r + (p0 + p1 + p2 + p3);
                o[h].x = o[h].x * r + p0 * vr[0].x + p1 * vr[1].x + p2 * vr[2].x + p3 * vr[3].x;
                o[h].y = o[h].y * r + p0 * vr[0].y + p1 * vr[1].y + p2 * vr[2].y + p3 * vr[3].y;
                o[h].z = o[h].z * r + p0 * vr[0].z + p1 * vr[1].z + p2 * vr[2].z + p3 * vr[3].z;
                o[h].w = o[h].w * r + p0 * vr[0].w + p1 * vr[1].w + p2 * vr[2].w + p3 * vr[3].w;
                m[h] = mnew;
            }
        }
    }

    // ---- merge the two halves (split-merge math), store partials ----
    float* pw = part + (size_t)((b * HKV + kvh) * NSPLIT + sp) * PART_STRIDE;
    #pragma unroll
    for (int h = 0; h < 4; ++h) {
        float mo = __shfl_xor(m[h], 32);
        float M  = fmaxf(m[h], mo);
        float f  = (m[h] > -INFINITY) ? __expf(m[h] - M) : 0.f;
        float lf = l[h] * f;
        float lt = lf + __shfl_xor(lf, 32);
        float ox = o[h].x * f, oy = o[h].y * f, oz = o[h].z * f, ow = o[h].w * f;
        ox += __shfl_xor(ox, 32);
        oy += __shfl_xor(oy, 32);
        oz += __shfl_xor(oz, 32);
        ow += __shfl_xor(ow, 32);
        float* pp = pw + h * HSTR;
        if (H == 0) {
            pp[c * 4 + 0] = ox; pp[c * 4 + 1] = oy;
            pp[c * 4 + 2] = oz; pp[c * 4 + 3] = ow;
        }
        if (lane == 0) { pp[128] = M; pp[129] = lt; }
    }
}

// ---------------- Kernel 3: combine split partials ---------------------------
__global__ void reduce_kernel(const float* __restrict__ part,
                              float* __restrict__ out)
{
    int blk = blockIdx.x;    // b*32 + hq
    int d   = threadIdx.x;   // 0..127
    int b   = blk >> 5;
    int hq  = blk & 31;
    int kvh = hq >> 2;
    int g   = hq & 3;
    const float* base = part + (size_t)((b * HKV + kvh) * NSPLIT) * PART_STRIDE + g * HSTR;

    float M = -INFINITY;
    #pragma unroll 8
    for (int s = 0; s < NSPLIT; ++s)
        M = fmaxf(M, base[(size_t)s * PART_STRIDE + 128]);
    float S = 0.f, acc = 0.f;
    #pragma unroll 8
    for (int s = 0; s < NSPLIT; ++s) {
        float ms = base[(size_t)s * PART_STRIDE + 128];
        float f  = __expf(ms - M);     // empty split: exp(-inf)=0; M finite (L>=1)
        S   += base[(size_t)s * PART_STRIDE + 129] * f;
        acc += base[(size_t)s * PART_STRIDE + d] * f;
    }
    out[(size_t)blk * DH + d] = acc / S;
}

extern "C" void kernel_launch(void* const* d_in, const int* in_sizes, int n_in,
                              void* d_out, int out_size, void* d_ws, size_t ws_size,
                              hipStream_t stream)
{
    const float* q    = (const float*)d_in[0];
    const float* knew = (const float*)d_in[1];
    const float* vnew = (const float*)d_in[2];
    const float* kc   = (const float*)d_in[3];
    const float* vc   = (const float*)d_in[4];
    const int*   bt   = (const int*)d_in[5];
    const int*   ctx  = (const int*)d_in[6];
    float* out = (float*)d_out;

    float* ws     = (float*)d_ws;
    float* q_rot  = ws;                              // 32*32*128 = 131072 f
    float* k_rot  = ws + 131072;                     // 32*8*128  =  32768 f
    int*   rowidx = (int*)(ws + 131072 + 32768);     // 32*2048   =  65536 i
    float* part   = ws + 131072 + 32768 + 65536;     // 8192*528  = 4325376 f

    prep_kernel<<<NB * MAXC / 256, 256, 0, stream>>>(q, knew, bt, ctx,
                                                     q_rot, k_rot, rowidx);
    attn_partial<<<NB * 2 * NSPLIT, 256, 0, stream>>>(
        kc, vc, vnew, ctx, q_rot, k_rot, rowidx, part);
    reduce_kernel<<<NB * NH, 128, 0, stream>>>(part, out);
}